// Round 4
// baseline (1044.049 us; speedup 1.0000x reference)
//
#include <hip/hip_runtime.h>

// ContrastiveLoss: prediction (2,16,32,256,256) fp32, gt (2,32,256,256) labels 0..50
// One-pass per-label accumulation of {sum(p) (16), sum(p/||p||) (16), count (1)},
// then tiny finalize kernel.
//
// Identity: cos_v = (p_v/||p_v||) . (m_l/||m_l||)  (eps clamp never binds)
// so intra_sum[l] = dot( sum_{v in l} p_v/||p_v|| , m_l ) / ||m_l||.
//
// R2 changes vs R1 (694us pass1, all pipes idle -> suspected flat atomics + no pipelining):
//  - LDS atomics via __hip_atomic_fetch_add on direct __shared__ array element,
//    workgroup scope => guaranteed ds_add_f32 (R1 went through a generic float*).
//  - manual 2-voxel software pipeline (R1 had #pragma unroll 1, no load overlap).
//  - 2048 blocks (was 1024) for latency hiding / tail balance.
// (Third submission: two GPUAcquisitionTimeouts, experiment still unexecuted.)

#define NL   51
#define SROW 33          // 16 sums | 16 nsums | 1 count
#define NREP 4           // replicated LDS tables: lane&3 -> table, cuts same-addr atomics
#define TAB  (NREP * NL * SROW)

#define LDSADD(idx, val) \
    __hip_atomic_fetch_add(&tab[idx], (val), __ATOMIC_RELAXED, __HIP_MEMORY_SCOPE_WORKGROUP)

__global__ __launch_bounds__(256) void cl_pass1(const float* __restrict__ pred,
                                                const int*   __restrict__ gt,
                                                float* __restrict__ gtab) {
    __shared__ float tab[TAB];
    for (int i = threadIdx.x; i < TAB; i += 256) tab[i] = 0.f;
    __syncthreads();

    const unsigned tid  = threadIdx.x;
    const unsigned rep  = tid & (NREP - 1);
    const unsigned base = blockIdx.x * 2048u;   // 2048 blocks * 2048 voxels = 4,194,304

    for (int k = 0; k < 8; k += 2) {
        // ---- load two voxels (A at k, B at k+1); loads independent, overlap ----
        unsigned nA = base + (unsigned)(k + 0) * 256u + tid;
        unsigned nB = base + (unsigned)(k + 1) * 256u + tid;
        const float* pA = pred + ((size_t)(nA >> 21) << 25) + (nA & 0x1FFFFFu);
        const float* pB = pred + ((size_t)(nB >> 21) << 25) + (nB & 0x1FFFFFu);

        float vA[16], vB[16];
        #pragma unroll
        for (int c = 0; c < 16; ++c) vA[c] = pA[(size_t)c << 21];
        #pragma unroll
        for (int c = 0; c < 16; ++c) vB[c] = pB[(size_t)c << 21];
        int idA = gt[nA];
        int idB = gt[nB];

        float ssA = 0.f, ssB = 0.f;
        #pragma unroll
        for (int c = 0; c < 16; ++c) ssA += vA[c] * vA[c];
        #pragma unroll
        for (int c = 0; c < 16; ++c) ssB += vB[c] * vB[c];
        float rnA = (ssA > 0.f) ? rsqrtf(ssA) : 0.f;
        float rnB = (ssB > 0.f) ? rsqrtf(ssB) : 0.f;

        // ---- accumulate voxel A ----
        {
            unsigned row = (rep * NL + (unsigned)idA) * SROW;
            #pragma unroll
            for (int c = 0; c < 16; ++c) {
                LDSADD(row + c,      vA[c]);
                LDSADD(row + 16 + c, vA[c] * rnA);
            }
            LDSADD(row + 32, 1.f);
        }
        // ---- accumulate voxel B ----
        {
            unsigned row = (rep * NL + (unsigned)idB) * SROW;
            #pragma unroll
            for (int c = 0; c < 16; ++c) {
                LDSADD(row + c,      vB[c]);
                LDSADD(row + 16 + c, vB[c] * rnB);
            }
            LDSADD(row + 32, 1.f);
        }
    }
    __syncthreads();

    for (int i = threadIdx.x; i < NL * SROW; i += 256) {
        float t = tab[i] + tab[NL*SROW + i] + tab[2*NL*SROW + i] + tab[3*NL*SROW + i];
        unsafeAtomicAdd(&gtab[i], t);
    }
}

__global__ __launch_bounds__(256) void cl_final(const float* __restrict__ gtab,
                                                float* __restrict__ out) {
    __shared__ float means[NL][16];
    __shared__ float mn[NL];
    __shared__ float cnt[NL];
    __shared__ float cmn[NL - 1][16];
    __shared__ float red[256];
    __shared__ float intra_s;
    const int t = threadIdx.x;

    if (t < NL) cnt[t] = gtab[t * SROW + 32];
    __syncthreads();

    for (int i = t; i < NL * 16; i += 256) {
        int l = i >> 4, c = i & 15;
        means[l][c] = gtab[l * SROW + c] / fmaxf(cnt[l], 1.0f);
    }
    __syncthreads();

    if (t < NL) {
        float s = 0.f;
        #pragma unroll
        for (int c = 0; c < 16; ++c) s += means[t][c] * means[t][c];
        mn[t] = sqrtf(s);
    }
    __syncthreads();

    // intra_per_label for labels 1..50
    float intra = 0.f;
    if (t < NL - 1) {
        int l = t + 1;
        float d = 0.f;
        #pragma unroll
        for (int c = 0; c < 16; ++c) d += gtab[l * SROW + 16 + c] * means[l][c];
        float isum = (mn[l] > 0.f) ? d / mn[l] : 0.f;
        intra = isum / fmaxf(cnt[l], 1.0f);
    }
    red[t] = intra;
    __syncthreads();
    for (int s = 128; s > 0; s >>= 1) { if (t < s) red[t] += red[t + s]; __syncthreads(); }
    if (t == 0) intra_s = red[0] / (float)(NL - 1);

    // normalized means for labels 1..50
    for (int i = t; i < (NL - 1) * 16; i += 256) {
        int l = (i >> 4) + 1, c = i & 15;
        cmn[i >> 4][c] = means[l][c] / fmaxf(mn[l], 1e-8f);
    }
    __syncthreads();

    // 1225 upper-triangle pairs among 50 labels
    float acc = 0.f;
    int k = 0;
    for (int i = 0; i < NL - 2; ++i)
        for (int j = i + 1; j < NL - 1; ++j) {
            if ((k & 255) == t) {
                float d = 0.f;
                #pragma unroll
                for (int c = 0; c < 16; ++c) d += cmn[i][c] * cmn[j][c];
                acc += fminf(fmaxf(d, 0.f), 1.f);
            }
            ++k;
        }
    red[t] = acc;
    __syncthreads();
    for (int s = 128; s > 0; s >>= 1) { if (t < s) red[t] += red[t + s]; __syncthreads(); }
    if (t == 0) out[0] = red[0] / 1225.f - intra_s;
}

extern "C" void kernel_launch(void* const* d_in, const int* in_sizes, int n_in,
                              void* d_out, int out_size, void* d_ws, size_t ws_size,
                              hipStream_t stream) {
    const float* pred = (const float*)d_in[0];
    const int*   gt   = (const int*)d_in[1];
    float* gtab = (float*)d_ws;

    hipMemsetAsync(gtab, 0, NL * SROW * sizeof(float), stream);
    cl_pass1<<<2048, 256, 0, stream>>>(pred, gt, gtab);
    cl_final<<<1, 256, 0, stream>>>(gtab, (float*)d_out);
}